// Round 1
// baseline (267.423 us; speedup 1.0000x reference)
//
#include <hip/hip_runtime.h>
#include <hip/hip_bf16.h>
#include <math.h>

#define NEXP  16
#define SEQ   512
#define PRED  720
#define NROWS 8192
#define NFREQ 256

typedef __bf16 bf16x8 __attribute__((ext_vector_type(8)));
typedef float  f32x4  __attribute__((ext_vector_type(4)));

// ---------------- K0: transpose + fp32->bf16 convert expert weights ----------------
// ew[e][l][p] (fp32) -> ewt[e][p][l] (bf16), so GEMM B tiles are k-contiguous.
__global__ __launch_bounds__(256) void k_transpose_ew(const float* __restrict__ ew,
                                                      __hip_bfloat16* __restrict__ ewt)
{
    __shared__ float tile[32][33];
    const int e  = blockIdx.z;
    const int p0 = blockIdx.x * 32;
    const int l0 = blockIdx.y * 32;
    const int tx = threadIdx.x & 31;
    const int ty = threadIdx.x >> 5;   // 0..7
    const float* src = ew + (size_t)e * SEQ * PRED;
#pragma unroll
    for (int i = 0; i < 4; ++i) {
        int l = l0 + ty + i * 8;
        int p = p0 + tx;
        tile[ty + i * 8][tx] = (p < PRED) ? src[(size_t)l * PRED + p] : 0.f;
    }
    __syncthreads();
    __hip_bfloat16* dst = ewt + (size_t)e * PRED * SEQ;
#pragma unroll
    for (int i = 0; i < 4; ++i) {
        int p = p0 + ty + i * 8;
        int l = l0 + tx;
        if (p < PRED) dst[(size_t)p * SEQ + l] = __float2bfloat16(tile[tx][ty + i * 8]);
    }
}

// ---------------- K1: per-row gating (fp64 FFT) + RevIN stats + xn (bf16) -------------
__global__ __launch_bounds__(256) void k_gate(const float* __restrict__ x,
                                              const float* __restrict__ gw,
                                              const float* __restrict__ gb,
                                              __hip_bfloat16* __restrict__ xn,
                                              float* __restrict__ meta,
                                              int* __restrict__ eidx,
                                              int* __restrict__ counts)
{
    __shared__ double re[512];
    __shared__ double im[512];
    __shared__ double ct[256];
    __shared__ double st[256];
    __shared__ double redd[8];
    __shared__ double gateS[NEXP];

    const int b = blockIdx.x;
    const int t = threadIdx.x;
    const float* xr = x + (size_t)b * SEQ;
    const float xa = xr[t];
    const float xb = xr[t + 256];

    // twiddle table: w_t = exp(-2*pi*i*t/512)
    {
        double ang = (double)t * (-6.283185307179586476925286766559 / 512.0);
        double sv, cv;
        sincos(ang, &sv, &cv);
        ct[t] = cv;
        st[t] = sv;
    }

    // mean / sumsq (fp64)
    double s1 = (double)xa + (double)xb;
    double s2 = (double)xa * (double)xa + (double)xb * (double)xb;
#pragma unroll
    for (int off = 32; off; off >>= 1) {
        s1 += __shfl_xor(s1, off);
        s2 += __shfl_xor(s2, off);
    }
    if ((t & 63) == 0) { redd[t >> 6] = s1; redd[4 + (t >> 6)] = s2; }
    __syncthreads();
    const double sum   = redd[0] + redd[1] + redd[2] + redd[3];
    const double sumsq = redd[4] + redd[5] + redd[6] + redd[7];
    const double mu = sum * (1.0 / SEQ);
    double var = sumsq * (1.0 / SEQ) - mu * mu;
    if (var < 0.0) var = 0.0;
    const double sd  = sqrt(var) + 1e-5;
    const double inv = 1.0 / sd;

    // bit-reversed store of x - mu (imag = 0)
    const double x0d = (double)xa - mu;
    const double x1d = (double)xb - mu;
    const int r0 = __brev((unsigned)t) >> 23;
    const int r1 = __brev((unsigned)(t + 256)) >> 23;
    re[r0] = x0d; im[r0] = 0.0;
    re[r1] = x1d; im[r1] = 0.0;

    // normalized row for the expert GEMM (bf16)
    xn[(size_t)b * SEQ + t]       = __float2bfloat16((float)(x0d * inv));
    xn[(size_t)b * SEQ + 256 + t] = __float2bfloat16((float)(x1d * inv));

    // iterative DIT radix-2 FFT, 9 stages
#pragma unroll
    for (int m = 2; m <= 512; m <<= 1) {
        __syncthreads();
        const int half = m >> 1;
        const int grp  = t / half;
        const int pos  = t & (half - 1);
        const int i0   = grp * m + pos;
        const int i1   = i0 + half;
        const int tw   = pos * (512 / m);
        const double wr = ct[tw], wi = st[tw];
        const double br = re[i1], bi = im[i1];
        const double tr = wr * br - wi * bi;
        const double ti = wr * bi + wi * br;
        const double ar = re[i0], ai = im[i0];
        re[i0] = ar + tr; im[i0] = ai + ti;
        re[i1] = ar - tr; im[i1] = ai - ti;
    }
    __syncthreads();

    // power spectrum (k = t, 0..255) and its sum
    const double P = re[t] * re[t] + im[t] * im[t];
    double ps = P;
#pragma unroll
    for (int off = 32; off; off >>= 1) ps += __shfl_xor(ps, off);
    if ((t & 63) == 0) redd[t >> 6] = ps;
    re[t] = P;                 // reuse re[0..255] to hold P
    __syncthreads();
    const double s = redd[0] + redd[1] + redd[2] + redd[3];

    // gate[e] = sum_k P[k]*gw[e][k]  (16 lanes per expert)
    const int e   = t >> 4;
    const int l16 = t & 15;
    const float* gwe = gw + e * NFREQ;
    double acc = 0.0;
#pragma unroll
    for (int i = 0; i < 16; ++i) {
        int k = l16 + (i << 4);
        acc += re[k] * (double)gwe[k];
    }
#pragma unroll
    for (int off = 8; off; off >>= 1) acc += __shfl_xor(acc, off, 16);
    if (l16 == 0) gateS[e] = acc;
    __syncthreads();

    if (t == 0) {
        const double sdiv  = (s == 0.0) ? 1.0 : s;
        const double inv_s = 1.0 / sdiv;
        double best = -1e300, best2 = -1e300;
        int i0b = 0, i1b = 0;
#pragma unroll
        for (int i = 0; i < NEXP; ++i) {
            double v = gateS[i] * inv_s + (double)gb[i];
            if (v > best)        { best2 = best; i1b = i0b; best = v; i0b = i; }
            else if (v > best2)  { best2 = v; i1b = i; }
        }
        const double eexp = exp(best2 - best);
        const double w0 = 1.0 / (1.0 + eexp);
        const double w1 = eexp / (1.0 + eexp);
        meta[b * 4 + 0] = (float)mu;
        meta[b * 4 + 1] = (float)(w0 * sd);
        meta[b * 4 + 2] = (float)(w1 * sd);
        meta[b * 4 + 3] = (float)sd;
        eidx[b * 2 + 0] = i0b;
        eidx[b * 2 + 1] = i1b;
        atomicAdd(&counts[i0b], 1);
        atomicAdd(&counts[NEXP + i1b], 1);
    }
}

// ---------------- K2: exclusive scan of 2x16 counts -> offsets, init cursors ---------
__global__ void k_scan(const int* __restrict__ counts, int* __restrict__ offs,
                       int* __restrict__ cursors)
{
    const int t = threadIdx.x;
    if (t < 2) {
        int base = t * NEXP, acc = 0;
        for (int i = 0; i < NEXP; ++i) {
            offs[base + i]    = acc;
            cursors[base + i] = acc;
            acc += counts[base + i];
        }
    }
}

// ---------------- K3: scatter row ids into per-(slot,expert) lists -------------------
__global__ __launch_bounds__(256) void k_scatter(const int* __restrict__ eidx,
                                                 int* __restrict__ cursors,
                                                 int* __restrict__ lists)
{
    const int b = blockIdx.x * 256 + threadIdx.x;
    if (b >= NROWS) return;
    const int e0 = eidx[2 * b];
    const int e1 = eidx[2 * b + 1];
    const int p0 = atomicAdd(&cursors[e0], 1);
    lists[p0] = b;
    const int p1 = atomicAdd(&cursors[NEXP + e1], 1);
    lists[NROWS + p1] = b;
}

// ---------------- K4/K5: grouped gather-GEMM per expert ------------------------------
// block: 64 rows x 64 cols, BK=32, 4 waves (each wave = 16 rows x 64 cols)
template <int SLOT>
__global__ __launch_bounds__(256) void k_expert_gemm(
    const __hip_bfloat16* __restrict__ xn, const __hip_bfloat16* __restrict__ ewt,
    const float* __restrict__ eb, const float* __restrict__ meta,
    const int* __restrict__ lists, const int* __restrict__ offs,
    const int* __restrict__ counts, float* __restrict__ out)
{
    const int e   = blockIdx.z;
    const int n_e = counts[SLOT * NEXP + e];
    const int rt  = blockIdx.y;
    if (rt * 64 >= n_e) return;
    const int ctile = blockIdx.x;      // 0..11 (cols of 64; last tile masked at 720)

    __shared__ __align__(16) __hip_bfloat16 As[64][40];  // [row][k] +8 pad
    __shared__ __align__(16) __hip_bfloat16 Bs[64][40];  // [col][k] +8 pad
    __shared__ int   rowB[64];
    __shared__ float rowMu[64];
    __shared__ float rowC[64];

    const int t = threadIdx.x;
    const int* list = lists + SLOT * NROWS + offs[SLOT * NEXP + e];
    if (t < 64) {
        int r  = rt * 64 + t;
        int bb = (r < n_e) ? list[r] : -1;
        rowB[t] = bb;
        if (bb >= 0) { rowMu[t] = meta[bb * 4]; rowC[t] = meta[bb * 4 + 1 + SLOT]; }
        else         { rowMu[t] = 0.f; rowC[t] = 0.f; }
    }
    __syncthreads();

    f32x4 acc[4];
    const f32x4 zero = {0.f, 0.f, 0.f, 0.f};
#pragma unroll
    for (int c = 0; c < 4; ++c) acc[c] = zero;

    const int arow = t >> 2, ach = t & 3;          // A staging: 64 rows x 4 chunks(8 bf16)
    const int bcol = t >> 2, bch = t & 3;          // B staging: 64 cols x 4 chunks
    const int gcol = ctile * 64 + bcol;
    const bool bvalid = (gcol < PRED);
    const int ab = rowB[arow];
    const __hip_bfloat16* asrc = (ab >= 0) ? (xn + (size_t)ab * SEQ) : xn;
    const __hip_bfloat16* bsrc = ewt + ((size_t)e * PRED + (bvalid ? gcol : 0)) * SEQ;

    const int wv = t >> 6, lane = t & 63;
    const int fr = lane & 15, fq = lane >> 4;

    for (int kk = 0; kk < 16; ++kk) {
        const int k0 = kk * 32;
        uint4 av, bv;
        if (ab >= 0) av = *(const uint4*)(asrc + k0 + ach * 8);
        else         av = uint4{0, 0, 0, 0};
        if (bvalid)  bv = *(const uint4*)(bsrc + k0 + bch * 8);
        else         bv = uint4{0, 0, 0, 0};
        __syncthreads();   // previous iteration's ds_reads done
        *(uint4*)&As[arow][ach * 8] = av;
        *(uint4*)&Bs[bcol][bch * 8] = bv;
        __syncthreads();
        const bf16x8 af = *(const bf16x8*)&As[wv * 16 + fr][fq * 8];
#pragma unroll
        for (int c = 0; c < 4; ++c) {
            const bf16x8 bf = *(const bf16x8*)&Bs[c * 16 + fr][fq * 8];
            acc[c] = __builtin_amdgcn_mfma_f32_16x16x32_bf16(af, bf, acc[c], 0, 0, 0);
        }
    }

    // epilogue: D row = fq*4 + r, col = fr  (m89-verified layout)
#pragma unroll
    for (int c = 0; c < 4; ++c) {
        const int col = ctile * 64 + c * 16 + fr;
        if (col >= PRED) continue;
        const float ebv = eb[e * PRED + col];
#pragma unroll
        for (int r = 0; r < 4; ++r) {
            const int rl = wv * 16 + fq * 4 + r;
            const int bb = rowB[rl];
            if (bb < 0) continue;
            const float v = acc[c][r] + ebv;
            float* op = out + (size_t)bb * PRED + col;
            if (SLOT == 0) *op = rowMu[rl] + rowC[rl] * v;
            else           *op += rowC[rl] * v;
        }
    }
}

// -------------------------------- launch ---------------------------------------------
extern "C" void kernel_launch(void* const* d_in, const int* in_sizes, int n_in,
                              void* d_out, int out_size, void* d_ws, size_t ws_size,
                              hipStream_t stream)
{
    const float* x  = (const float*)d_in[0];
    const float* gw = (const float*)d_in[1];
    const float* gb = (const float*)d_in[2];
    const float* ew = (const float*)d_in[3];
    const float* eb = (const float*)d_in[4];
    float* out = (float*)d_out;
    char*  ws  = (char*)d_ws;

    constexpr size_t XN_OFF   = 0;
    constexpr size_t XN_SZ    = (size_t)NROWS * SEQ * 2;          // 8,388,608
    constexpr size_t EWT_OFF  = XN_OFF + XN_SZ;
    constexpr size_t EWT_SZ   = (size_t)NEXP * PRED * SEQ * 2;    // 11,796,480
    constexpr size_t META_OFF = EWT_OFF + EWT_SZ;
    constexpr size_t META_SZ  = (size_t)NROWS * 4 * 4;            // 131,072
    constexpr size_t EIDX_OFF = META_OFF + META_SZ;
    constexpr size_t EIDX_SZ  = (size_t)NROWS * 2 * 4;            // 65,536
    constexpr size_t LIST_OFF = EIDX_OFF + EIDX_SZ;
    constexpr size_t LIST_SZ  = (size_t)2 * NROWS * 4;            // 65,536
    constexpr size_t CNT_OFF  = LIST_OFF + LIST_SZ;
    constexpr size_t OFFS_OFF = CNT_OFF + 128;
    constexpr size_t CURS_OFF = OFFS_OFF + 128;

    __hip_bfloat16* xn   = (__hip_bfloat16*)(ws + XN_OFF);
    __hip_bfloat16* ewt  = (__hip_bfloat16*)(ws + EWT_OFF);
    float* meta  = (float*)(ws + META_OFF);
    int* eidx    = (int*)(ws + EIDX_OFF);
    int* lists   = (int*)(ws + LIST_OFF);
    int* counts  = (int*)(ws + CNT_OFF);
    int* offs    = (int*)(ws + OFFS_OFF);
    int* cursors = (int*)(ws + CURS_OFF);

    hipMemsetAsync(counts, 0, 128, stream);

    k_transpose_ew<<<dim3(23, 16, NEXP), dim3(256), 0, stream>>>(ew, ewt);
    k_gate<<<dim3(NROWS), dim3(256), 0, stream>>>(x, gw, gb, xn, meta, eidx, counts);
    k_scan<<<dim3(1), dim3(64), 0, stream>>>(counts, offs, cursors);
    k_scatter<<<dim3(NROWS / 256), dim3(256), 0, stream>>>(eidx, cursors, lists);
    k_expert_gemm<0><<<dim3(12, 128, NEXP), dim3(256), 0, stream>>>(
        xn, ewt, eb, meta, lists, offs, counts, out);
    k_expert_gemm<1><<<dim3(12, 128, NEXP), dim3(256), 0, stream>>>(
        xn, ewt, eb, meta, lists, offs, counts, out);
}